// Round 9
// baseline (681.433 us; speedup 1.0000x reference)
//
#include <hip/hip_runtime.h>

typedef _Float16 half8 __attribute__((ext_vector_type(8)));
typedef _Float16 half4_t __attribute__((ext_vector_type(4)));
typedef float f32x4 __attribute__((ext_vector_type(4)));

#define ROWS 131072   // B*S
#define BM   64       // rows per block
#define NBLK 2048     // ROWS / BM

// exact-erf GELU via Abramowitz-Stegun 7.1.26 (|err| <= 1.5e-7)
__device__ __forceinline__ float gelu_erf(float y) {
  float x  = y * 0.70710678118654752440f;
  float ax = fabsf(x);
  float t  = 1.0f / (1.0f + 0.3275911f * ax);
  float poly = ((((1.061405429f * t - 1.453152027f) * t + 1.421413741f) * t
                 - 0.284496736f) * t + 0.254829592f) * t;
  float e = __expf(-ax * ax);
  float erfv = copysignf(1.0f - poly * e, x);
  return 0.5f * y * (1.0f + erfv);
}

// ---- Kernel 1: W prep: Wh[f,d]=fp16(gamma[d]*W[f,d]); u[f]=sum(gamma*W);
//      c[f]=sum(beta*W). One wave per output row f. (R8-verified) -----------
__global__ __launch_bounds__(256) void wprep_kernel(
    const float* __restrict__ W, const float* __restrict__ gamma,
    const float* __restrict__ beta,
    _Float16* __restrict__ Wh, float* __restrict__ u, float* __restrict__ c)
{
  const int lane = threadIdx.x & 63;
  const int wave = threadIdx.x >> 6;
  const int f = blockIdx.x * 4 + wave;          // 256 blocks x 4 waves = 1024 rows
  const float4 g  = ((const float4*)gamma)[lane];
  const float4 be = ((const float4*)beta)[lane];
  const float4 w  = ((const float4*)(W + (size_t)f * 256))[lane];
  float4 gw; gw.x = g.x * w.x; gw.y = g.y * w.y; gw.z = g.z * w.z; gw.w = g.w * w.w;
  half4_t h;
  h[0] = (_Float16)gw.x; h[1] = (_Float16)gw.y;
  h[2] = (_Float16)gw.z; h[3] = (_Float16)gw.w;
  ((half4_t*)(Wh + (size_t)f * 256))[lane] = h;
  float su = gw.x + gw.y + gw.z + gw.w;
  float sc = be.x * w.x + be.y * w.y + be.z * w.z + be.w * w.w;
#pragma unroll
  for (int off = 32; off > 0; off >>= 1) {
    su += __shfl_xor(su, off, 64);
    sc += __shfl_xor(sc, off, 64);
  }
  if (lane == 0) { u[f] = su; c[f] = sc; }
}

// ---- Kernel 2: FULLY FUSED, deferred-LN, LEAN 8-wave version ---------------
// 512 threads = 8 waves (4m x 2n); each wave owns 16 rows x 64 cols per nt.
// Per-wave state: afr[8] (32 VGPR) + acc[4] (16) + bf[4] (16) -> high occupancy.
// All index formulas are R8-verified with the i-dimension removed.
__global__ __launch_bounds__(512) void fused_kernel(
    const float* __restrict__ xa, const float* __restrict__ xb,
    const _Float16* __restrict__ Wh, const float* __restrict__ u,
    const float* __restrict__ c, const float* __restrict__ bias,
    float* __restrict__ out)
{
  const int lane = threadIdx.x & 63;
  const int wave = threadIdx.x >> 6;      // 0..7
  const int wm = wave >> 1;               // 0..3: 16-row block
  const int wn = wave & 1;                // 0..1: 64-col half
  const size_t m0 = (size_t)blockIdx.x * BM;
  const int h = lane >> 4;                // k-chunk selector
  const int lr = lane & 15;

  // ---- Phase A: load own fragment's x, v=a+b -> fp16 fragment + fp32 stats --
  half8 afr[8];
  const size_t row = m0 + (size_t)(wm * 16 + lr);
  const float4* pa = (const float4*)(xa + row * 256);
  const float4* pb = (const float4*)(xb + row * 256);
  float s = 0.f, s2 = 0.f;
#pragma unroll
  for (int ks = 0; ks < 8; ++ks) {
    const int c4 = ks * 8 + h * 2;        // float4 index of k = ks*32 + h*8
    float4 a0 = pa[c4],     b0 = pb[c4];
    float4 a1 = pa[c4 + 1], b1 = pb[c4 + 1];
    float v0 = a0.x + b0.x, v1 = a0.y + b0.y, v2 = a0.z + b0.z, v3 = a0.w + b0.w;
    float v4 = a1.x + b1.x, v5 = a1.y + b1.y, v6 = a1.z + b1.z, v7 = a1.w + b1.w;
    s  += v0 + v1 + v2 + v3 + v4 + v5 + v6 + v7;
    s2 += v0*v0 + v1*v1 + v2*v2 + v3*v3 + v4*v4 + v5*v5 + v6*v6 + v7*v7;
    half8 hv;
    hv[0] = (_Float16)v0; hv[1] = (_Float16)v1; hv[2] = (_Float16)v2; hv[3] = (_Float16)v3;
    hv[4] = (_Float16)v4; hv[5] = (_Float16)v5; hv[6] = (_Float16)v6; hv[7] = (_Float16)v7;
    afr[ks] = hv;
  }
  // 4-lane row-group reduction (lanes l, l^16, l^32, l^48 share a row)
  s  += __shfl_xor(s,  16, 64);  s  += __shfl_xor(s,  32, 64);
  s2 += __shfl_xor(s2, 16, 64);  s2 += __shfl_xor(s2, 32, 64);
  const float mean = s * (1.0f / 256.0f);
  const float var  = s2 * (1.0f / 256.0f) - mean * mean;
  const float rs   = rsqrtf(var + 1e-12f);
  const float rm   = rs * mean;

  const float4* bias4 = (const float4*)bias;
  const float4* u4p   = (const float4*)u;
  const float4* c4p   = (const float4*)c;

  // ---- Phase C: 8 n-chunks of 128 cols; B from global (L2-hot) --------------
#pragma unroll 1
  for (int nt = 0; nt < 8; ++nt) {
    const int n0 = nt * 128;
    f32x4 acc[4] = {};
#pragma unroll
    for (int ks = 0; ks < 8; ++ks) {
      half8 bf[4];
#pragma unroll
      for (int j = 0; j < 4; ++j) {
        const int col = n0 + wn * 64 + j * 16 + lr;
        bf[j] = *(const half8*)(Wh + (size_t)col * 256 + ks * 32 + h * 8);
      }
#pragma unroll
      for (int j = 0; j < 4; ++j)
        acc[j] = __builtin_amdgcn_mfma_f32_16x16x32_f16(bf[j], afr[ks], acc[j], 0, 0, 0);
    }
    // epilogue: y = rs*acc - rm*u + (c + bias), exact GELU, float4 store
#pragma unroll
    for (int j = 0; j < 4; ++j) {
      const int col0 = n0 + wn * 64 + j * 16 + h * 4;
      const float4 bv = bias4[col0 >> 2];
      const float4 uv = u4p[col0 >> 2];
      const float4 cv = c4p[col0 >> 2];
      float4 st;
      st.x = gelu_erf(fmaf(rs, acc[j][0], fmaf(-rm, uv.x, cv.x + bv.x)));
      st.y = gelu_erf(fmaf(rs, acc[j][1], fmaf(-rm, uv.y, cv.y + bv.y)));
      st.z = gelu_erf(fmaf(rs, acc[j][2], fmaf(-rm, uv.z, cv.z + bv.z)));
      st.w = gelu_erf(fmaf(rs, acc[j][3], fmaf(-rm, uv.w, cv.w + bv.w)));
      *(float4*)(out + row * 1024 + col0) = st;
    }
  }
}

extern "C" void kernel_launch(void* const* d_in, const int* in_sizes, int n_in,
                              void* d_out, int out_size, void* d_ws, size_t ws_size,
                              hipStream_t stream) {
  const float* x399  = (const float*)d_in[0];
  const float* x365  = (const float*)d_in[1];
  const float* gamma = (const float*)d_in[2];
  const float* beta  = (const float*)d_in[3];
  const float* W     = (const float*)d_in[4];
  const float* bias  = (const float*)d_in[5];
  float* out = (float*)d_out;

  _Float16* Wh = (_Float16*)d_ws;                   // 512 KiB
  float* u = (float*)(Wh + (size_t)1024 * 256);     // 4 KiB
  float* c = u + 1024;                              // 4 KiB

  wprep_kernel<<<256, 256, 0, stream>>>(W, gamma, beta, Wh, u, c);
  fused_kernel<<<NBLK, 512, 0, stream>>>(x399, x365, Wh, u, c, bias, out);
}